// Round 6
// baseline (351.823 us; speedup 1.0000x reference)
//
#include <hip/hip_runtime.h>
#include <stdint.h>

// HardNegLoss: N=8192 rows, C=5000 classes.
// loss = [ sum_pos (softplus(x)-x) + sum_{top-k negatives by pred} softplus(x) ] / sum(target)
// k = min(3*pos, C-pos). Top-k of raw pred among negatives == reference's
// argsort-of-(softmax - target) selection; ties by count (value-exact).
//
// Structure: one WAVE per row. Wave-private LDS; no __syncthreads, no shared
// counters. Compaction = ballot + mbcnt-prefix + uniform register counter.

#define C_DIM 5000
#define C4_DIM 1250
#define BLK 256
#define WSCAP 768         // staged candidates/wave (~523 expected, +11.6 sigma)
#define CUT 1.25f         // stage negatives > CUT; exact global fallback otherwise
#define NSLOT 64

// within-wave phase fence: drain own LDS ops + compiler memory barrier
#define WSYNC() asm volatile("s_waitcnt lgkmcnt(0)" ::: "memory")

__device__ __forceinline__ float sp_f(float x) {
    // softplus via HW v_exp_f32/v_log_f32 (rel err ~1e-6 vs 0.158 tolerance)
    return fmaxf(x, 0.0f) + __logf(1.0f + __expf(-fabsf(x)));
}
__device__ __forceinline__ uint32_t mono_u(float x) {
    uint32_t b = __float_as_uint(x);
    return b ^ ((b & 0x80000000u) ? 0xFFFFFFFFu : 0x80000000u);
}
__device__ __forceinline__ float unmono_f(uint32_t u) {
    uint32_t b = (u & 0x80000000u) ? (u ^ 0x80000000u) : ~u;
    return __uint_as_float(b);
}
__device__ __forceinline__ int vbin_of(float x) {
    // linear bins width 1/128 over [CUT, CUT+2): ~2-3 staged values per bin
    int v = (int)((x - CUT) * 128.0f);
    return v > 255 ? 255 : (v < 0 ? 0 : v);
}

// crossing bin for kp-th largest from wave-private 256-bin hist (bins high=large).
// Exactly one lane writes misc[0]=bin, misc[1]=count strictly above it.
__device__ __forceinline__ void find_bin_w(const unsigned int* h, int kp, int lane, int* misc) {
    int c0 = (int)h[4 * lane + 0];
    int c1 = (int)h[4 * lane + 1];
    int c2 = (int)h[4 * lane + 2];
    int c3 = (int)h[4 * lane + 3];
    int lsum = c0 + c1 + c2 + c3;
    int s = lsum;
    #pragma unroll
    for (int off = 1; off < 64; off <<= 1) {
        int o = __shfl_down(s, off);
        if (lane + off < 64) s += o;
    }
    int above = s - lsum;              // count in strictly-higher bins
    if (above < kp && kp <= s) {
        int b, ab;
        if (kp <= above + c3)                { b = 4 * lane + 3; ab = above; }
        else if (kp <= above + c3 + c2)      { b = 4 * lane + 2; ab = above + c3; }
        else if (kp <= above + c3 + c2 + c1) { b = 4 * lane + 1; ab = above + c3 + c2; }
        else                                 { b = 4 * lane;     ab = above + c3 + c2 + c1; }
        misc[0] = b;
        misc[1] = ab;
    }
}

__global__ __launch_bounds__(BLK, 6) void hardneg_kernel(
    const float* __restrict__ pred, const float* __restrict__ target,
    char* __restrict__ ws)
{
    __shared__ uint32_t s_buf[4][WSCAP];
    __shared__ unsigned int s_hist[4][256];
    __shared__ uint32_t s_tiny[4][64];
    __shared__ int s_misc[4][4];

    const int lane = threadIdx.x & 63;
    const int wv = threadIdx.x >> 6;
    const int row = blockIdx.x * 4 + wv;

    uint32_t* sbuf = s_buf[wv];
    unsigned int* h = s_hist[wv];
    int* misc = s_misc[wv];

    const float4* pr4 = (const float4*)(pred + (size_t)row * C_DIM);
    const float4* tg4 = (const float4*)(target + (size_t)row * C_DIM);

    h[lane] = 0; h[lane + 64] = 0; h[lane + 128] = 0; h[lane + 192] = 0;
    WSYNC();

    float acc = 0.0f;
    int pcnt = 0;
    unsigned wcnt = 0;     // wave-uniform candidate count (register, no LDS)
    const unsigned long long ltmask = (1ull << lane) - 1ull;

    // ---- hot pass: coalesced loads, ballot-compaction, inline wave-private hist ----
    #define PROC(xv, tv) do {                                                  \
        float x_ = (xv);                                                       \
        bool ispos_ = ((tv) != 0.0f);                                          \
        bool cand_ = (!ispos_) && (x_ > CUT);                                  \
        unsigned long long m_ = __ballot(cand_);                               \
        if (cand_) {                                                           \
            unsigned slot_ = wcnt + (unsigned)__popcll(m_ & ltmask);           \
            if (slot_ < WSCAP) sbuf[slot_] = __float_as_uint(x_) ^ 0x80000000u;\
            atomicAdd(&h[vbin_of(x_)], 1u);                                    \
        }                                                                      \
        wcnt += (unsigned)__popcll(m_);                                        \
        if (ispos_) { pcnt++; acc += sp_f(x_) - x_; }                          \
    } while (0)

    #pragma unroll 4
    for (int c = 0; c < 19; ++c) {
        int idx = c * 64 + lane;
        float4 p = pr4[idx];
        float4 t = tg4[idx];
        PROC(p.x, t.x); PROC(p.y, t.y); PROC(p.z, t.z); PROC(p.w, t.w);
    }
    {   // tail: 1216 + lane, valid for lane < 34
        int idx = 19 * 64 + lane;
        float4 p = {0.f, 0.f, 0.f, 0.f}, t = {0.f, 0.f, 0.f, 0.f};
        if (idx < C4_DIM) { p = pr4[idx]; t = tg4[idx]; }
        PROC(p.x, t.x); PROC(p.y, t.y); PROC(p.z, t.z); PROC(p.w, t.w);
    }
    #undef PROC

    // wave totals (butterfly -> all lanes)
    int pt = pcnt;
    #pragma unroll
    for (int off = 32; off; off >>= 1) pt += __shfl_xor(pt, off);
    const int pos_total = pt;
    const int k = min(3 * pos_total, C_DIM - pos_total);
    const int cnt = (int)wcnt;
    if (k == 0) return;    // wave-uniform; no barriers anywhere -> safe

    WSYNC();               // staged writes + hist atomics now visible

    uint32_t tu;
    int n_at;
    const bool fb = (k > cnt) || (cnt > WSCAP);   // wave-uniform

    if (!fb) {
        // ---- crossing value-bin from the inline hist ----
        find_bin_w(h, k, lane, misc);
        WSYNC();
        const int bv = misc[0];
        const int kp = k - misc[1];

        // ---- gather crossing-bin elements (expected ~3) via ballot-compaction ----
        unsigned tcnt = 0;
        const int bound = (cnt + 63) & ~63;       // all lanes stay in step for ballot
        for (int i = lane; i < bound; i += 64) {
            bool in = (i < cnt);
            uint32_t u = in ? sbuf[i] : 0u;
            bool hit = in && (vbin_of(unmono_f(u)) == bv);
            unsigned long long m = __ballot(hit);
            if (hit) {
                unsigned idx = tcnt + (unsigned)__popcll(m & ltmask);
                if (idx < 64) s_tiny[wv][idx] = u;
            }
            tcnt += (unsigned)__popcll(m);
        }
        WSYNC();

        if (tcnt <= 64) {
            // exact rank among <=64 values, in-register
            uint32_t ul = (lane < (int)tcnt) ? s_tiny[wv][lane] : 0u;
            int sg = 0, eq = 0;
            for (int j = 0; j < (int)tcnt; ++j) {
                uint32_t uj = (uint32_t)__shfl((int)ul, j);
                sg += (uj > ul);
                eq += (uj == ul);
            }
            if (lane < (int)tcnt && sg < kp && kp <= sg + eq) {
                misc[2] = (int)ul;     // tie-group lanes write identical values
                misc[3] = kp - sg;
            }
            WSYNC();
            tu = (uint32_t)misc[2];
            n_at = misc[3];
        } else {
            // robust: exact 8-bit radix within bin bv over staged values (wave-local)
            uint32_t prefix = 0;
            int kq = kp;
            for (int r = 0; r < 4; ++r) {
                const int shift = 24 - 8 * r;
                WSYNC();
                h[lane] = 0; h[lane + 64] = 0; h[lane + 128] = 0; h[lane + 192] = 0;
                WSYNC();
                for (int i = lane; i < cnt; i += 64) {
                    uint32_t u = sbuf[i];
                    bool match = (vbin_of(unmono_f(u)) == bv);
                    if (r > 0) match = match && ((u >> (shift + 8)) == (prefix >> (shift + 8)));
                    if (match) atomicAdd(&h[(u >> shift) & 255u], 1u);
                }
                WSYNC();
                find_bin_w(h, kq, lane, misc);
                WSYNC();
                prefix |= ((uint32_t)misc[0]) << shift;
                kq -= misc[1];
            }
            tu = prefix;
            n_at = kq;
        }

        // ---- final: sum softplus over staged selected (u > tu) ----
        for (int i = lane; i < cnt; i += 64) {
            uint32_t u = sbuf[i];
            if (u > tu) acc += sp_f(unmono_f(u));
        }
    } else {
        // ---- cold exact fallback (k > staged or overflow): wave-local radix over
        //      all negatives, re-reading global (L2/L3-resident). Never for this data.
        uint32_t prefix = 0;
        int kq = k;
        for (int r = 0; r < 4; ++r) {
            const int shift = 24 - 8 * r;
            WSYNC();
            h[lane] = 0; h[lane + 64] = 0; h[lane + 128] = 0; h[lane + 192] = 0;
            WSYNC();
            for (int i = lane; i < C4_DIM; i += 64) {
                float4 p = pr4[i];
                float4 t = tg4[i];
                float xs[4] = {p.x, p.y, p.z, p.w};
                float tsv[4] = {t.x, t.y, t.z, t.w};
                #pragma unroll
                for (int j = 0; j < 4; ++j) {
                    if (tsv[j] == 0.0f) {
                        uint32_t u = mono_u(xs[j]);
                        bool m = (r == 0) || ((u >> (shift + 8)) == (prefix >> (shift + 8)));
                        if (m) atomicAdd(&h[(u >> shift) & 255u], 1u);
                    }
                }
            }
            WSYNC();
            find_bin_w(h, kq, lane, misc);
            WSYNC();
            prefix |= ((uint32_t)misc[0]) << shift;
            kq -= misc[1];
        }
        tu = prefix;
        n_at = kq;
        for (int i = lane; i < C4_DIM; i += 64) {
            float4 p = pr4[i];
            float4 t = tg4[i];
            float xs[4] = {p.x, p.y, p.z, p.w};
            float tsv[4] = {t.x, t.y, t.z, t.w};
            #pragma unroll
            for (int j = 0; j < 4; ++j) {
                if (tsv[j] == 0.0f && mono_u(xs[j]) > tu) acc += sp_f(xs[j]);
            }
        }
    }

    // ---- wave reduce + slot-hashed global accumulate ----
    #pragma unroll
    for (int off = 32; off; off >>= 1) acc += __shfl_down(acc, off);
    if (lane == 0) {
        float rowsum = acc + (float)n_at * sp_f(unmono_f(tu));
        char* slot = ws + (size_t)(row & (NSLOT - 1)) * 16;
        atomicAdd((double*)slot, (double)rowsum);
        atomicAdd((float*)(slot + 8), (float)pos_total);   // exact: int-valued < 2^24
    }
}

__global__ void hardneg_finalize(const char* __restrict__ ws, float* __restrict__ out)
{
    const int l = threadIdx.x;   // 64 threads
    double n = *(const double*)(ws + (size_t)l * 16);
    float d = *(const float*)(ws + (size_t)l * 16 + 8);
    #pragma unroll
    for (int off = 32; off; off >>= 1) {
        n += __shfl_down(n, off);
        d += __shfl_down(d, off);
    }
    if (l == 0) out[0] = (d > 0.0f) ? (float)(n / (double)d) : 0.0f;
}

extern "C" void kernel_launch(void* const* d_in, const int* in_sizes, int n_in,
                              void* d_out, int out_size, void* d_ws, size_t ws_size,
                              hipStream_t stream) {
    const float* pred = (const float*)d_in[0];
    const float* target = (const float*)d_in[1];
    float* out = (float*)d_out;
    char* ws = (char*)d_ws;

    // d_ws re-poisoned to 0xAA before every timed launch -> zero the 64 slots
    hipMemsetAsync(ws, 0, NSLOT * 16, stream);

    const int nrows = in_sizes[0] / C_DIM;   // 8192
    hardneg_kernel<<<nrows / 4, BLK, 0, stream>>>(pred, target, ws);
    hardneg_finalize<<<1, 64, 0, stream>>>(ws, out);
}

// Round 7
// 346.245 us; speedup vs baseline: 1.0161x; 1.0161x over previous
//
#include <hip/hip_runtime.h>
#include <stdint.h>

// HardNegLoss: N=8192 rows, C=5000 classes.
// loss = [ sum_pos (softplus(x)-x) + sum_{top-k negatives by pred} softplus(x) ] / sum(target)
// k = min(3*pos, C-pos). Top-k of raw pred among negatives == reference's
// argsort-of-(softmax - target) selection; ties by count (value-exact).
//
// Structure: one WAVE per row, 4 waves/block, no __syncthreads.
// Streaming via global_load_lds double-buffered tiles + counted vmcnt (per-wave).

#define C_DIM 5000
#define C4_DIM 1250
#define BLK 256
#define WSCAP 768         // staged candidates/wave (~523 expected, +11.6 sigma)
#define CUT 1.25f         // stage negatives > CUT; exact fallbacks otherwise
#define NSLOT 128
#define TILE_F 512        // floats per tile per array (2 KB)
#define NTILE 9           // 9*512 = 4608; tail = 392 floats

#define WSYNC()  asm volatile("s_waitcnt lgkmcnt(0)" ::: "memory")
#define CFENCE() asm volatile("" ::: "memory")

__device__ __forceinline__ void gload16(const void* g, void* l) {
    // async global->LDS, 16B/lane: LDS dest = uniform base + lane*16
    __builtin_amdgcn_global_load_lds(
        (const __attribute__((address_space(1))) void*)g,
        (__attribute__((address_space(3))) void*)l, 16, 0, 0);
}

__device__ __forceinline__ float sp_f(float x) {
    // softplus via HW v_exp_f32/v_log_f32 (rel err ~1e-6 vs 0.158 tolerance)
    return fmaxf(x, 0.0f) + __logf(1.0f + __expf(-fabsf(x)));
}
__device__ __forceinline__ uint32_t mono_u(float x) {
    uint32_t b = __float_as_uint(x);
    return b ^ ((b & 0x80000000u) ? 0xFFFFFFFFu : 0x80000000u);
}
__device__ __forceinline__ float unmono_f(uint32_t u) {
    uint32_t b = (u & 0x80000000u) ? (u ^ 0x80000000u) : ~u;
    return __uint_as_float(b);
}
__device__ __forceinline__ int vbin_of(float x) {
    // linear bins width 1/128 over [CUT, CUT+2): ~2-3 staged values per bin
    int v = (int)((x - CUT) * 128.0f);
    return v > 255 ? 255 : (v < 0 ? 0 : v);
}

// crossing bin for kp-th largest from wave-private 256-bin hist (bins high=large).
// Exactly one lane writes misc[0]=bin, misc[1]=count strictly above it.
__device__ __forceinline__ void find_bin_w(const unsigned int* h, int kp, int lane, int* misc) {
    int c0 = (int)h[4 * lane + 0];
    int c1 = (int)h[4 * lane + 1];
    int c2 = (int)h[4 * lane + 2];
    int c3 = (int)h[4 * lane + 3];
    int lsum = c0 + c1 + c2 + c3;
    int s = lsum;
    #pragma unroll
    for (int off = 1; off < 64; off <<= 1) {
        int o = __shfl_down(s, off);
        if (lane + off < 64) s += o;
    }
    int above = s - lsum;              // count in strictly-higher bins
    if (above < kp && kp <= s) {
        int b, ab;
        if (kp <= above + c3)                { b = 4 * lane + 3; ab = above; }
        else if (kp <= above + c3 + c2)      { b = 4 * lane + 2; ab = above + c3; }
        else if (kp <= above + c3 + c2 + c1) { b = 4 * lane + 1; ab = above + c3 + c2; }
        else                                 { b = 4 * lane;     ab = above + c3 + c2 + c1; }
        misc[0] = b;
        misc[1] = ab;
    }
}

__global__ __launch_bounds__(BLK, 3) void hardneg_kernel(
    const float* __restrict__ pred, const float* __restrict__ target,
    char* __restrict__ ws)
{
    __shared__ float s_tileP[4][2][TILE_F];   // 16 KB: pred tiles, dbuf per wave
    __shared__ float s_tileT[4][2][TILE_F];   // 16 KB: target tiles
    __shared__ uint32_t s_buf[4][WSCAP];      // 12 KB: staged mono-u candidates
    __shared__ unsigned int s_hist[4][256];   // 4 KB
    __shared__ uint32_t s_tiny[4][64];
    __shared__ int s_misc[4][4];

    const int lane = threadIdx.x & 63;
    const int wv = threadIdx.x >> 6;
    const int row = blockIdx.x * 4 + wv;

    uint32_t* sbuf = s_buf[wv];
    unsigned int* h = s_hist[wv];
    int* misc = s_misc[wv];

    const float4* pr4 = (const float4*)(pred + (size_t)row * C_DIM);
    const float4* tg4 = (const float4*)(target + (size_t)row * C_DIM);

    h[lane] = 0; h[lane + 64] = 0; h[lane + 128] = 0; h[lane + 192] = 0;
    WSYNC();

    float acc = 0.0f;
    int pcnt = 0;
    unsigned wcnt = 0;     // wave-uniform candidate count (register, no LDS counter)
    const unsigned long long ltmask = (1ull << lane) - 1ull;

    #define PROC(xv, tv) do {                                                  \
        float x_ = (xv);                                                       \
        bool ispos_ = ((tv) != 0.0f);                                          \
        bool cand_ = (!ispos_) && (x_ > CUT);                                  \
        unsigned long long m_ = __ballot(cand_);                               \
        if (cand_) {                                                           \
            unsigned slot_ = wcnt + (unsigned)__popcll(m_ & ltmask);           \
            if (slot_ < WSCAP) sbuf[slot_] = __float_as_uint(x_) ^ 0x80000000u;\
            atomicAdd(&h[vbin_of(x_)], 1u);                                    \
        }                                                                      \
        wcnt += (unsigned)__popcll(m_);                                        \
        if (ispos_) { pcnt++; acc += sp_f(x_) - x_; }                          \
    } while (0)

    // ---- tail first (direct loads, fully consumed before pipeline) ----
    {
        int i0 = NTILE * (TILE_F / 4) + lane;          // 1152+lane < 1250 for all lanes
        float4 p = pr4[i0];
        float4 t = tg4[i0];
        PROC(p.x, t.x); PROC(p.y, t.y); PROC(p.z, t.z); PROC(p.w, t.w);
        int i1 = i0 + 64;                              // valid for lane < 34
        float4 q = {0.f, 0.f, 0.f, 0.f}, s = {0.f, 0.f, 0.f, 0.f};
        if (i1 < C4_DIM) { q = pr4[i1]; s = tg4[i1]; }
        PROC(q.x, s.x); PROC(q.y, s.y); PROC(q.z, s.z); PROC(q.w, s.w);
    }
    asm volatile("s_waitcnt vmcnt(0)" ::: "memory");   // exact vmcnt baseline
    __builtin_amdgcn_sched_barrier(0);

    // ---- double-buffered async pipeline over 9 full tiles ----
    auto issue_tile = [&](int t) {
        const char* gp = (const char*)(pr4 + (size_t)t * (TILE_F / 4));
        const char* gt = (const char*)(tg4 + (size_t)t * (TILE_F / 4));
        char* lp = (char*)&s_tileP[wv][t & 1][0];
        char* lt = (char*)&s_tileT[wv][t & 1][0];
        gload16(gp + (size_t)lane * 16,        lp);
        gload16(gp + 1024 + (size_t)lane * 16, lp + 1024);
        gload16(gt + (size_t)lane * 16,        lt);
        gload16(gt + 1024 + (size_t)lane * 16, lt + 1024);
    };

    issue_tile(0);
    issue_tile(1);
    for (int t = 0; t < NTILE; ++t) {
        if (t < NTILE - 1) { asm volatile("s_waitcnt vmcnt(4)" ::: "memory"); }
        else               { asm volatile("s_waitcnt vmcnt(0)" ::: "memory"); }
        __builtin_amdgcn_sched_barrier(0);
        {
            const float4* bp = (const float4*)&s_tileP[wv][t & 1][0];
            const float4* bt = (const float4*)&s_tileT[wv][t & 1][0];
            float4 p0 = bp[lane],      t0 = bt[lane];
            float4 p1 = bp[lane + 64], t1 = bt[lane + 64];
            PROC(p0.x, t0.x); PROC(p0.y, t0.y); PROC(p0.z, t0.z); PROC(p0.w, t0.w);
            PROC(p1.x, t1.x); PROC(p1.y, t1.y); PROC(p1.z, t1.z); PROC(p1.w, t1.w);
        }
        CFENCE();                      // keep buffer reads before the refill below
        if (t + 2 < NTILE) issue_tile(t + 2);
    }
    #undef PROC

    // ---- wave totals ----
    int pt = pcnt;
    #pragma unroll
    for (int off = 32; off; off >>= 1) pt += __shfl_xor(pt, off);
    const int pos_total = pt;
    const int k = min(3 * pos_total, C_DIM - pos_total);
    const int cnt = (int)wcnt;
    if (k == 0) return;    // wave-uniform; no barriers anywhere -> safe

    WSYNC();               // staged writes + hist atomics visible

    uint32_t tu;
    int n_at;
    const bool fb = (k > cnt) || (cnt > WSCAP);   // wave-uniform

    if (!fb) {
        find_bin_w(h, k, lane, misc);
        WSYNC();
        const int bv = misc[0];
        const int kp = k - misc[1];

        // gather crossing-bin elements (expected ~3) via ballot-compaction
        unsigned tcnt = 0;
        const int bound = (cnt + 63) & ~63;
        for (int i = lane; i < bound; i += 64) {
            bool in = (i < cnt);
            uint32_t u = in ? sbuf[i] : 0u;
            bool hit = in && (vbin_of(unmono_f(u)) == bv);
            unsigned long long m = __ballot(hit);
            if (hit) {
                unsigned idx = tcnt + (unsigned)__popcll(m & ltmask);
                if (idx < 64) s_tiny[wv][idx] = u;
            }
            tcnt += (unsigned)__popcll(m);
        }
        WSYNC();

        if (tcnt <= 64) {
            // exact rank among <=64 values, in-register
            uint32_t ul = (lane < (int)tcnt) ? s_tiny[wv][lane] : 0u;
            int sg = 0, eq = 0;
            for (int j = 0; j < (int)tcnt; ++j) {
                uint32_t uj = (uint32_t)__shfl((int)ul, j);
                sg += (uj > ul);
                eq += (uj == ul);
            }
            if (lane < (int)tcnt && sg < kp && kp <= sg + eq) {
                misc[2] = (int)ul;     // tie-group lanes write identical values
                misc[3] = kp - sg;
            }
            WSYNC();
            tu = (uint32_t)misc[2];
            n_at = misc[3];
        } else {
            // robust: exact 8-bit radix within bin bv over staged values
            uint32_t prefix = 0;
            int kq = kp;
            for (int r = 0; r < 4; ++r) {
                const int shift = 24 - 8 * r;
                WSYNC();
                h[lane] = 0; h[lane + 64] = 0; h[lane + 128] = 0; h[lane + 192] = 0;
                WSYNC();
                for (int i = lane; i < cnt; i += 64) {
                    uint32_t u = sbuf[i];
                    bool match = (vbin_of(unmono_f(u)) == bv);
                    if (r > 0) match = match && ((u >> (shift + 8)) == (prefix >> (shift + 8)));
                    if (match) atomicAdd(&h[(u >> shift) & 255u], 1u);
                }
                WSYNC();
                find_bin_w(h, kq, lane, misc);
                WSYNC();
                prefix |= ((uint32_t)misc[0]) << shift;
                kq -= misc[1];
            }
            tu = prefix;
            n_at = kq;
        }

        for (int i = lane; i < cnt; i += 64) {
            uint32_t u = sbuf[i];
            if (u > tu) acc += sp_f(unmono_f(u));
        }
    } else {
        // cold exact fallback (k > staged or overflow): wave-local radix over all
        // negatives, re-reading global. Never taken for this data.
        uint32_t prefix = 0;
        int kq = k;
        for (int r = 0; r < 4; ++r) {
            const int shift = 24 - 8 * r;
            WSYNC();
            h[lane] = 0; h[lane + 64] = 0; h[lane + 128] = 0; h[lane + 192] = 0;
            WSYNC();
            for (int i = lane; i < C4_DIM; i += 64) {
                float4 p = pr4[i];
                float4 t = tg4[i];
                float xs[4] = {p.x, p.y, p.z, p.w};
                float tsv[4] = {t.x, t.y, t.z, t.w};
                #pragma unroll
                for (int j = 0; j < 4; ++j) {
                    if (tsv[j] == 0.0f) {
                        uint32_t u = mono_u(xs[j]);
                        bool m = (r == 0) || ((u >> (shift + 8)) == (prefix >> (shift + 8)));
                        if (m) atomicAdd(&h[(u >> shift) & 255u], 1u);
                    }
                }
            }
            WSYNC();
            find_bin_w(h, kq, lane, misc);
            WSYNC();
            prefix |= ((uint32_t)misc[0]) << shift;
            kq -= misc[1];
        }
        tu = prefix;
        n_at = kq;
        for (int i = lane; i < C4_DIM; i += 64) {
            float4 p = pr4[i];
            float4 t = tg4[i];
            float xs[4] = {p.x, p.y, p.z, p.w};
            float tsv[4] = {t.x, t.y, t.z, t.w};
            #pragma unroll
            for (int j = 0; j < 4; ++j) {
                if (tsv[j] == 0.0f && mono_u(xs[j]) > tu) acc += sp_f(xs[j]);
            }
        }
    }

    // ---- wave reduce + slot-hashed global accumulate ----
    #pragma unroll
    for (int off = 32; off; off >>= 1) acc += __shfl_down(acc, off);
    if (lane == 0) {
        float rowsum = acc + (float)n_at * sp_f(unmono_f(tu));
        char* slot = ws + (size_t)(row & (NSLOT - 1)) * 32;
        atomicAdd((double*)slot, (double)rowsum);
        atomicAdd((float*)(slot + 8), (float)pos_total);   // exact: int-valued < 2^24
    }
}

__global__ void hardneg_finalize(const char* __restrict__ ws, float* __restrict__ out)
{
    const int l = threadIdx.x;   // 64 threads
    double n = 0.0;
    float d = 0.0f;
    #pragma unroll
    for (int s = 0; s < NSLOT / 64; ++s) {
        const char* slot = ws + (size_t)(s * 64 + l) * 32;
        n += *(const double*)slot;
        d += *(const float*)(slot + 8);
    }
    #pragma unroll
    for (int off = 32; off; off >>= 1) {
        n += __shfl_down(n, off);
        d += __shfl_down(d, off);
    }
    if (l == 0) out[0] = (d > 0.0f) ? (float)(n / (double)d) : 0.0f;
}

extern "C" void kernel_launch(void* const* d_in, const int* in_sizes, int n_in,
                              void* d_out, int out_size, void* d_ws, size_t ws_size,
                              hipStream_t stream) {
    const float* pred = (const float*)d_in[0];
    const float* target = (const float*)d_in[1];
    float* out = (float*)d_out;
    char* ws = (char*)d_ws;

    // d_ws re-poisoned to 0xAA before every timed launch -> zero the slots
    hipMemsetAsync(ws, 0, NSLOT * 32, stream);

    const int nrows = in_sizes[0] / C_DIM;   // 8192
    hardneg_kernel<<<nrows / 4, BLK, 0, stream>>>(pred, target, ws);
    hardneg_finalize<<<1, 64, 0, stream>>>(ws, out);
}

// Round 8
// 332.698 us; speedup vs baseline: 1.0575x; 1.0407x over previous
//
#include <hip/hip_runtime.h>
#include <stdint.h>

// HardNegLoss: N=8192 rows, C=5000 classes.
// loss = [ sum_pos (softplus(x)-x) + sum_{top-k negatives by pred} softplus(x) ] / sum(target)
// k = min(3*pos, C-pos). Top-k of raw pred among negatives == reference's
// argsort-of-(softmax - target) selection; ties by count (value-exact).
//
// Block-per-row. Hot loop: 1 fma classify + private-stride LDS staging
// (sbuf[tid + j*256]) -- no ballots, no atomic-returns, no cross-lane deps.

#define C_DIM 5000
#define C4_DIM 1250
#define BLK 256
#define CCAP 10           // per-thread staged candidates (mean 1.34)
#define PCAP 6            // per-thread staged positives (mean 0.2)
#define CUT 1.5f          // stage negatives > CUT (~334/row); k<=~250 whp
#define NSLOT 128

__device__ __forceinline__ float sp_f(float x) {
    // softplus via HW v_exp_f32/v_log_f32 (rel err ~1e-6 vs 0.158 tolerance)
    return fmaxf(x, 0.0f) + __logf(1.0f + __expf(-fabsf(x)));
}
__device__ __forceinline__ uint32_t mono_u(float x) {
    uint32_t b = __float_as_uint(x);
    return b ^ ((b & 0x80000000u) ? 0xFFFFFFFFu : 0x80000000u);
}
__device__ __forceinline__ float unmono_f(uint32_t u) {
    uint32_t b = (u & 0x80000000u) ? (u ^ 0x80000000u) : ~u;
    return __uint_as_float(b);
}
__device__ __forceinline__ int vbin_of(float x) {
    // linear bins width 1/128 over [CUT, CUT+2); threshold in [1.8, 3.4] whp
    int v = (int)((x - CUT) * 128.0f);
    return v > 255 ? 255 : (v < 0 ? 0 : v);
}

// crossing bin for kp-th largest from 256-bin hist (bins high=large), wave 0.
// s_sel[0]=bin, s_sel[1]=count strictly above it.
__device__ __forceinline__ void find_bin(const unsigned int* hist, int kp, int tid, int* s_sel) {
    if (tid < 64) {
        int c0 = (int)hist[4 * tid + 0];
        int c1 = (int)hist[4 * tid + 1];
        int c2 = (int)hist[4 * tid + 2];
        int c3 = (int)hist[4 * tid + 3];
        int lsum = c0 + c1 + c2 + c3;
        int s = lsum;
        #pragma unroll
        for (int off = 1; off < 64; off <<= 1) {
            int o = __shfl_down(s, off);
            if (tid + off < 64) s += o;
        }
        int above = s - lsum;
        if (above < kp && kp <= s) {
            int b, ab;
            if (kp <= above + c3)                { b = 4 * tid + 3; ab = above; }
            else if (kp <= above + c3 + c2)      { b = 4 * tid + 2; ab = above + c3; }
            else if (kp <= above + c3 + c2 + c1) { b = 4 * tid + 1; ab = above + c3 + c2; }
            else                                 { b = 4 * tid;     ab = above + c3 + c2 + c1; }
            s_sel[0] = b;
            s_sel[1] = ab;
        }
    }
}

__global__ __launch_bounds__(BLK, 6) void hardneg_kernel(
    const float* __restrict__ pred, const float* __restrict__ target,
    char* __restrict__ ws)
{
    __shared__ uint32_t sbuf[CCAP * BLK];   // slot tid + j*256 (mono-u values)
    __shared__ uint32_t pbuf[PCAP * BLK];   // slot tid + j*256 (raw f32 bits)
    __shared__ unsigned int hist[256];
    __shared__ unsigned int w_scr[4];
    __shared__ float f_scr[4];
    __shared__ int s_sel[2];
    __shared__ int s_misc[4];               // [0]=tcnt, [1]=tu, [2]=n_at, [3]=overflow
    __shared__ uint32_t s_tiny[64];

    const int tid = threadIdx.x;
    const int lane = tid & 63;
    const int wv = tid >> 6;
    const int row = blockIdx.x;
    const float4* pr4 = (const float4*)(pred + (size_t)row * C_DIM);
    const float4* tg4 = (const float4*)(target + (size_t)row * C_DIM);

    hist[tid] = 0;
    if (tid < 4) s_misc[tid] = 0;
    __syncthreads();

    // ---- issue all 10 loads up front (named regs; compiler schedules waits) ----
    float4 a0 = pr4[tid];        float4 b0 = tg4[tid];
    float4 a1 = pr4[tid + 256];  float4 b1 = tg4[tid + 256];
    float4 a2 = pr4[tid + 512];  float4 b2 = tg4[tid + 512];
    float4 a3 = pr4[tid + 768];  float4 b3 = tg4[tid + 768];
    float4 a4 = {0.f, 0.f, 0.f, 0.f}, b4 = {0.f, 0.f, 0.f, 0.f};
    if (tid < C4_DIM - 1024) { a4 = pr4[tid + 1024]; b4 = tg4[tid + 1024]; }

    int mc = 0, mp = 0;
    // y = x for negatives (t=0 -> fma exact); y ~ x-512 for positives
    #define PE(xv, tv) do {                                                       \
        float y_ = fmaf((tv), -512.0f, (xv));                                     \
        if (y_ > CUT) {                                                           \
            if (mc < CCAP) sbuf[tid + (mc << 8)] = __float_as_uint(y_) ^ 0x80000000u; \
            ++mc;                                                                 \
        } else if (y_ < -100.0f) {                                                \
            if (mp < PCAP) pbuf[tid + (mp << 8)] = __float_as_uint(xv);           \
            ++mp;                                                                 \
        }                                                                         \
    } while (0)

    PE(a0.x, b0.x); PE(a0.y, b0.y); PE(a0.z, b0.z); PE(a0.w, b0.w);
    PE(a1.x, b1.x); PE(a1.y, b1.y); PE(a1.z, b1.z); PE(a1.w, b1.w);
    PE(a2.x, b2.x); PE(a2.y, b2.y); PE(a2.z, b2.z); PE(a2.w, b2.w);
    PE(a3.x, b3.x); PE(a3.y, b3.y); PE(a3.z, b3.z); PE(a3.w, b3.w);
    PE(a4.x, b4.x); PE(a4.y, b4.y); PE(a4.z, b4.z); PE(a4.w, b4.w);
    #undef PE

    // ---- block totals: packed (cand | pos<<16); overflow flag ----
    if (mc > CCAP || mp > PCAP) atomicOr(&s_misc[3], 1);
    unsigned pk = (unsigned)mc | ((unsigned)mp << 16);
    #pragma unroll
    for (int off = 32; off; off >>= 1) pk += (unsigned)__shfl_xor((int)pk, off);
    if (lane == 0) w_scr[wv] = pk;
    __syncthreads();
    const unsigned tot = w_scr[0] + w_scr[1] + w_scr[2] + w_scr[3];
    const int cnt = (int)(tot & 0xFFFFu);          // true candidate count (uncapped)
    const int pos_total = (int)(tot >> 16);        // true positive count (uncapped)
    const int k = min(3 * pos_total, C_DIM - pos_total);
    if (k == 0) return;                            // block-uniform exit

    const bool fb = (s_misc[3] != 0) || (k > cnt); // block-uniform
    float acc = 0.0f;
    uint32_t tu;
    int n_at;

    if (!fb) {
        // ---- positives (~50/row, own slots) ----
        for (int j = 0; j < mp; ++j) {
            float x = __uint_as_float(pbuf[tid + (j << 8)]);
            acc += sp_f(x) - x;
        }
        // ---- hist over staged candidates (own slots, ~1.3 iters/thread) ----
        for (int j = 0; j < mc; ++j)
            atomicAdd(&hist[vbin_of(unmono_f(sbuf[tid + (j << 8)]))], 1u);
        __syncthreads();
        find_bin(hist, k, tid, s_sel);
        __syncthreads();
        const int bv = s_sel[0];
        const int kp = k - s_sel[1];

        // ---- gather crossing-bin elements (expected ~3) ----
        for (int j = 0; j < mc; ++j) {
            uint32_t u = sbuf[tid + (j << 8)];
            if (vbin_of(unmono_f(u)) == bv) {
                int idx = atomicAdd(&s_misc[0], 1);
                if (idx < 64) s_tiny[idx] = u;
            }
        }
        __syncthreads();
        const int tcnt = s_misc[0];

        if (tcnt <= 64) {
            // exact rank among <=64 values on wave 0
            if (tid < 64) {
                uint32_t ul = (lane < tcnt) ? s_tiny[lane] : 0u;
                int sg = 0, eq = 0;
                for (int j = 0; j < tcnt; ++j) {
                    uint32_t uj = (uint32_t)__shfl((int)ul, j);
                    sg += (uj > ul);
                    eq += (uj == ul);
                }
                if (lane < tcnt && sg < kp && kp <= sg + eq) {
                    s_misc[1] = (int)ul;    // tie-group lanes write identical values
                    s_misc[2] = kp - sg;
                }
            }
            __syncthreads();
            tu = (uint32_t)s_misc[1];
            n_at = s_misc[2];
        } else {
            // robust: exact 8-bit radix within bin bv over staged values
            uint32_t prefix = 0;
            int kq = kp;
            for (int r = 0; r < 4; ++r) {
                const int shift = 24 - 8 * r;
                __syncthreads();
                hist[tid] = 0;
                __syncthreads();
                for (int j = 0; j < mc; ++j) {
                    uint32_t u = sbuf[tid + (j << 8)];
                    bool match = (vbin_of(unmono_f(u)) == bv);
                    if (r > 0) match = match && ((u >> (shift + 8)) == (prefix >> (shift + 8)));
                    if (match) atomicAdd(&hist[(u >> shift) & 255u], 1u);
                }
                __syncthreads();
                find_bin(hist, kq, tid, s_sel);
                __syncthreads();
                prefix |= ((uint32_t)s_sel[0]) << shift;
                kq -= s_sel[1];
            }
            tu = prefix;
            n_at = kq;
        }

        // ---- final: sum softplus over staged selected (u > tu) ----
        for (int j = 0; j < mc; ++j) {
            uint32_t u = sbuf[tid + (j << 8)];
            if (u > tu) acc += sp_f(unmono_f(u));
        }
    } else {
        // ---- cold exact fallback (overflow or k > cnt): full re-read.
        //      Recomputes positives too (pbuf may be incomplete). ----
        acc = 0.0f;
        uint32_t prefix = 0;
        int kq = k;
        for (int r = 0; r < 4; ++r) {
            const int shift = 24 - 8 * r;
            __syncthreads();
            hist[tid] = 0;
            __syncthreads();
            for (int i = tid; i < C4_DIM; i += BLK) {
                float4 p = pr4[i];
                float4 t = tg4[i];
                float xs[4] = {p.x, p.y, p.z, p.w};
                float tsv[4] = {t.x, t.y, t.z, t.w};
                #pragma unroll
                for (int j = 0; j < 4; ++j) {
                    if (tsv[j] == 0.0f) {
                        uint32_t u = mono_u(xs[j]);
                        bool m = (r == 0) || ((u >> (shift + 8)) == (prefix >> (shift + 8)));
                        if (m) atomicAdd(&hist[(u >> shift) & 255u], 1u);
                    }
                }
            }
            __syncthreads();
            find_bin(hist, kq, tid, s_sel);
            __syncthreads();
            prefix |= ((uint32_t)s_sel[0]) << shift;
            kq -= s_sel[1];
        }
        tu = prefix;
        n_at = kq;
        for (int i = tid; i < C4_DIM; i += BLK) {
            float4 p = pr4[i];
            float4 t = tg4[i];
            float xs[4] = {p.x, p.y, p.z, p.w};
            float tsv[4] = {t.x, t.y, t.z, t.w};
            #pragma unroll
            for (int j = 0; j < 4; ++j) {
                if (tsv[j] != 0.0f) acc += sp_f(xs[j]) - xs[j];
                else if (mono_u(xs[j]) > tu) acc += sp_f(xs[j]);
            }
        }
    }

    // ---- block reduce + slot-hashed global accumulate ----
    #pragma unroll
    for (int off = 32; off; off >>= 1) acc += __shfl_down(acc, off);
    if (lane == 0) f_scr[wv] = acc;
    __syncthreads();
    if (tid == 0) {
        float rowsum = f_scr[0] + f_scr[1] + f_scr[2] + f_scr[3]
                     + (float)n_at * sp_f(unmono_f(tu));
        char* slot = ws + (size_t)(row & (NSLOT - 1)) * 32;
        atomicAdd((double*)slot, (double)rowsum);
        atomicAdd((float*)(slot + 8), (float)pos_total);   // exact: int-valued < 2^24
    }
}

__global__ void hardneg_finalize(const char* __restrict__ ws, float* __restrict__ out)
{
    const int l = threadIdx.x;   // 64 threads
    double n = 0.0;
    float d = 0.0f;
    #pragma unroll
    for (int s = 0; s < NSLOT / 64; ++s) {
        const char* slot = ws + (size_t)(s * 64 + l) * 32;
        n += *(const double*)slot;
        d += *(const float*)(slot + 8);
    }
    #pragma unroll
    for (int off = 32; off; off >>= 1) {
        n += __shfl_down(n, off);
        d += __shfl_down(d, off);
    }
    if (l == 0) out[0] = (d > 0.0f) ? (float)(n / (double)d) : 0.0f;
}

extern "C" void kernel_launch(void* const* d_in, const int* in_sizes, int n_in,
                              void* d_out, int out_size, void* d_ws, size_t ws_size,
                              hipStream_t stream) {
    const float* pred = (const float*)d_in[0];
    const float* target = (const float*)d_in[1];
    float* out = (float*)d_out;
    char* ws = (char*)d_ws;

    // d_ws re-poisoned to 0xAA before every timed launch -> zero the slots
    hipMemsetAsync(ws, 0, NSLOT * 32, stream);

    const int nrows = in_sizes[0] / C_DIM;   // 8192
    hardneg_kernel<<<nrows, BLK, 0, stream>>>(pred, target, ws);
    hardneg_finalize<<<1, 64, 0, stream>>>(ws, out);
}